// Round 7
// baseline (146.362 us; speedup 1.0000x reference)
//
#include <hip/hip_runtime.h>

#define NSTEP 64
#define HDIM 1024
#define BDIM 2048
#define OHH 511

typedef float v2f __attribute__((ext_vector_type(2)));
typedef float v4f __attribute__((ext_vector_type(4)));

__device__ __forceinline__ v2f vsplat(float s) { v2f r; r.x = s; r.y = s; return r; }

// Wave-level DPP lane shifts (single VALU op; proven exact + neutral-cost).
__device__ __forceinline__ float dpp_up1(float v) {   // lane n <- lane n-1
    int i = __builtin_bit_cast(int, v);
    int r = __builtin_amdgcn_update_dpp(i, i, 0x138, 0xF, 0xF, false);  // wave_shr:1
    return __builtin_bit_cast(float, r);
}
__device__ __forceinline__ float dpp_dn1(float v) {   // lane n <- lane n+1
    int i = __builtin_bit_cast(int, v);
    int r = __builtin_amdgcn_update_dpp(i, i, 0x130, 0xF, 0xF, false);  // wave_shl:1
    return __builtin_bit_cast(float, r);
}

// ---------------------------------------------------------------------------
// Kernel 1: merged coefficient table (R5 layout, unchanged):
//   ctab[s*1024 + slot]        even pair p, slot = ((p&7)<<6)|(p>>3)
//   ctab[s*1024 + 512 + slot]  odd  pair j, same slot formula; j==511 -> identity
//   wtab[q][lane] float4 = (cw0,sw0,cw1,sw1) for cols (16*lane+2q, +2q+1)
// ---------------------------------------------------------------------------
__global__ void coeff_kernel(const float* __restrict__ omega,
                             const float* __restrict__ ETh,
                             const float* __restrict__ OTh,
                             const float* __restrict__ EPh,
                             const float* __restrict__ OPh,
                             float4* __restrict__ ctab,
                             float2* __restrict__ wtab)
{
    int idx = blockIdx.x * 256 + threadIdx.x;
    if (idx < NSTEP * 512) {
        int s = idx >> 9;
        int p = idx & 511;
        float c, sn, cp, sp;
        __sincosf(ETh[idx], &sn, &c);
        __sincosf(EPh[idx], &sp, &cp);
        ctab[(s << 10) | ((p & 7) << 6) | (p >> 3)] = make_float4(c, sn, sp, cp);
    } else if (idx < 2 * NSTEP * 512) {
        int i2 = idx - NSTEP * 512;
        int s = i2 >> 9;
        int j = i2 & 511;
        float4 v;
        if (j < OHH) {
            float c, sn, cp, sp;
            __sincosf(OTh[s * OHH + j], &sn, &c);
            __sincosf(OPh[s * OHH + j], &sp, &cp);
            v = make_float4(c, sn, sp, cp);
        } else {
            v = make_float4(1.f, 0.f, 1.f, 0.f);  // identity rotation
        }
        ctab[(s << 10) | 512 | ((j & 7) << 6) | (j >> 3)] = v;
    } else if (idx < 2 * NSTEP * 512 + HDIM) {
        int c = idx - 2 * NSTEP * 512;
        float cw, sw;
        __sincosf(omega[c], &sw, &cw);
        int p = c >> 1;
        wtab[(((p & 7) << 6) | (p >> 3)) * 2 + (c & 1)] = make_float2(cw, sw);
    }
}

// Packed complex pair rotation: state A,B are (re,im) v2f; f = (c,sn,sp,cp).
//   t = c*A - sn*B;  B' = c*B + sn*A;  A' = (sp + i*cp) * t
__device__ __forceinline__ void pair_rot(const v4f f, v2f& A, v2f& B) {
    v2f C = vsplat(f.x), S = vsplat(f.y);
    v2f t = C * A - S * B;
    B = C * B + S * A;
    v2f cps; cps.x = -f.w; cps.y = f.w;
    A = vsplat(f.z) * t + cps * t.yx;
}
// Right-boundary variant: update A only, Bn is neighbor's value.
__device__ __forceinline__ void pair_rot_a(const v4f f, v2f& A, const v2f Bn) {
    v2f t = vsplat(f.x) * A - vsplat(f.y) * Bn;
    v2f cps; cps.x = -f.w; cps.y = f.w;
    A = vsplat(f.z) * t + cps * t.yx;
}

// ---------------------------------------------------------------------------
// Kernel 2: ONE ROW PER WAVE — the clean 2-waves/SIMD test.
//
// Model after R0/R3/R5/R6 (all 2200-2400 cyc/step, VALUBusy 42-47%,
// regardless of delivery pipe): the wall is per-wave ISSUE throughput, not
// delivery. Every prior variant ran 1 wave/SIMD; a lone wave issues ~1
// instr/4-5 cyc (issue cadence + dep bubbles), so ~410 VALU instr/step ->
// ~2100 cyc — the invariant wall. Fix: halve per-wave work (1 row/wave),
// double waves (512 blocks x 4 waves = 2048 waves = 8/CU = 2/SIMD), keep
// waves fully independent: no barrier, no LDS, no cross-wave anything.
// Body/tables byte-identical to the R5-verified math (oc0-via-DPP, DPP
// boundaries, cur/nxt one-step-ahead prefetch, plain L1 loads).
// Known-risk alternative outcome: if the L1 return path (~64 B/cyc/CU) is
// a hard cap, doubled coeff traffic (128 KB/CU/step) lands neutral ~2050
// cyc/step — that result discriminates cleanly (next: LDS-share coeffs).
// ---------------------------------------------------------------------------
__global__ __launch_bounds__(256, 2) void eunn_kernel(
    const float* __restrict__ x_re,
    const float* __restrict__ x_im,
    const float4* __restrict__ ctab,
    const float4* __restrict__ wtab,
    float* __restrict__ out)
{
    const int lane = threadIdx.x & 63;
    const int wave = threadIdx.x >> 6;
    const int row  = blockIdx.x * 4 + wave;   // 1 row per wave
    const int colbase = lane << 4;

    v2f x[16];   // interleaved (re, im) state: 32 VGPRs

    // current / next step coefficient register sets (16 float4 each)
    v4f cec[8], coc[8];
    v4f nec[8], noc[8];

    // --- prologue: issue step-0 coefficient loads first
    {
        const float4* b = ctab + lane;
        #pragma unroll
        for (int k = 0; k < 8; ++k) cec[k] = *reinterpret_cast<const v4f*>(b + (k << 6));
        #pragma unroll
        for (int k = 0; k < 8; ++k) coc[k] = *reinterpret_cast<const v4f*>(b + 512 + (k << 6));
    }

    // --- load state (f32 planes), interleave into v2f regs ---
    {
        const float4* pr = reinterpret_cast<const float4*>(x_re + row * HDIM + colbase);
        const float4* pi = reinterpret_cast<const float4*>(x_im + row * HDIM + colbase);
        #pragma unroll
        for (int q = 0; q < 4; ++q) {
            float4 vr = pr[q];
            float4 vi = pi[q];
            x[4*q+0].x = vr.x; x[4*q+0].y = vi.x;
            x[4*q+1].x = vr.y; x[4*q+1].y = vi.y;
            x[4*q+2].x = vr.z; x[4*q+2].y = vi.z;
            x[4*q+3].x = vr.w; x[4*q+3].y = vi.w;
        }
    }

    // one full step's math (R5-verified body, single row)
    auto body = [&](const v4f (&ec)[8], const v4f (&oc)[8]) {
        // ---- even layer, boundary pairs first (k=0,7)
        pair_rot(ec[0], x[0],  x[1]);
        pair_rot(ec[7], x[14], x[15]);

        // boundary exchange on post-even values via DPP
        v2f xn, xl;
        xn.x = dpp_dn1(x[0].x);     // right neighbor's col0
        xn.y = dpp_dn1(x[0].y);
        xl.x = dpp_up1(x[15].x);    // left neighbor's col15
        xl.y = dpp_up1(x[15].y);

        // oc0 (left-boundary coeffs = lane-1's oc[7]) via DPP; lane0 -> identity
        float c0 = dpp_up1(oc[7].x);
        float s0 = dpp_up1(oc[7].y);
        if (lane == 0) { c0 = 1.0f; s0 = 0.0f; }

        // remaining even pairs k=1..6
        #pragma unroll
        for (int k = 1; k < 7; ++k)
            pair_rot(ec[k], x[2*k], x[2*k+1]);

        // ---- odd layer: internal pairs oc[k-1] -> local cols (2k-1, 2k)
        #pragma unroll
        for (int k = 1; k < 8; ++k)
            pair_rot(oc[k-1], x[2*k-1], x[2*k]);
        // right boundary: update col15 (lane63: oc[7] identity pad, sn=0)
        pair_rot_a(oc[7], x[15], xn);
        // left boundary: update col0 (lane0: forced identity above)
        {
            v2f C = vsplat(c0), S = vsplat(s0);
            x[0] = C * x[0] + S * xl;
        }
    };

    // 2-step unrolled main loop; coefficient loads issued one full step
    // before first use, pinned by sched_barrier so they cannot sink.
    for (int s = 0; s < NSTEP; s += 2) {
        {   // prefetch step s+1 -> n-set
            const float4* b = ctab + ((s + 1) << 10) + lane;
            #pragma unroll
            for (int k = 0; k < 8; ++k) nec[k] = *reinterpret_cast<const v4f*>(b + (k << 6));
            #pragma unroll
            for (int k = 0; k < 8; ++k) noc[k] = *reinterpret_cast<const v4f*>(b + 512 + (k << 6));
        }
        __builtin_amdgcn_sched_barrier(0);
        body(cec, coc);

        {   // prefetch step s+2 -> c-set (clamped; last-iter loads unused but valid)
            int s2 = (s + 2 < NSTEP) ? (s + 2) : (NSTEP - 1);
            const float4* b = ctab + (s2 << 10) + lane;
            #pragma unroll
            for (int k = 0; k < 8; ++k) cec[k] = *reinterpret_cast<const v4f*>(b + (k << 6));
            #pragma unroll
            for (int k = 0; k < 8; ++k) coc[k] = *reinterpret_cast<const v4f*>(b + 512 + (k << 6));
        }
        __builtin_amdgcn_sched_barrier(0);
        body(nec, noc);
    }

    // --- omega phase + de-interleave + store (coalesced) ---
    float4 wc[8];
    #pragma unroll
    for (int q = 0; q < 8; ++q) wc[q] = wtab[(q << 6) + lane];  // (cw0,sw0,cw1,sw1) cols 2q,2q+1

    {
        float4* pre = reinterpret_cast<float4*>(out + row * HDIM + colbase);
        float4* pim = reinterpret_cast<float4*>(out + BDIM * HDIM + row * HDIM + colbase);
        #pragma unroll
        for (int h = 0; h < 4; ++h) {
            float4 wa = wc[2*h];      // cols 4h, 4h+1
            float4 wb = wc[2*h + 1];  // cols 4h+2, 4h+3
            v2f X0 = x[4*h+0], X1 = x[4*h+1], X2 = x[4*h+2], X3 = x[4*h+3];
            float4 vr, vi;
            vr.x = X0.x * wa.x - X0.y * wa.y;  vi.x = X0.x * wa.y + X0.y * wa.x;
            vr.y = X1.x * wa.z - X1.y * wa.w;  vi.y = X1.x * wa.w + X1.y * wa.z;
            vr.z = X2.x * wb.x - X2.y * wb.y;  vi.z = X2.x * wb.y + X2.y * wb.x;
            vr.w = X3.x * wb.z - X3.y * wb.w;  vi.w = X3.x * wb.w + X3.y * wb.z;
            pre[h] = vr;
            pim[h] = vi;
        }
    }
}

extern "C" void kernel_launch(void* const* d_in, const int* in_sizes, int n_in,
                              void* d_out, int out_size, void* d_ws, size_t ws_size,
                              hipStream_t stream)
{
    const float* x_re  = (const float*)d_in[0];
    const float* x_im  = (const float*)d_in[1];
    const float* omega = (const float*)d_in[2];
    const float* eth   = (const float*)d_in[3];
    const float* oth   = (const float*)d_in[4];
    const float* eph   = (const float*)d_in[5];
    const float* oph   = (const float*)d_in[6];

    char* ws = (char*)d_ws;
    float4* ctab = (float4*)ws;                             // 64*1024*16 = 1 MB
    float2* wtab = (float2*)(ws + NSTEP * 1024 * 16);       // 8 KB

    coeff_kernel<<<260, 256, 0, stream>>>(omega, eth, oth, eph, oph, ctab, wtab);
    eunn_kernel<<<BDIM / 4, 256, 0, stream>>>(x_re, x_im, ctab,
                                              (const float4*)wtab, (float*)d_out);
}

// Round 8
// 126.367 us; speedup vs baseline: 1.1582x; 1.1582x over previous
//
#include <hip/hip_runtime.h>

#define NSTEP 64
#define HDIM 1024
#define BDIM 2048
#define OHH 511

typedef float v2f __attribute__((ext_vector_type(2)));

__device__ __forceinline__ v2f vsplat(float s) { v2f r; r.x = s; r.y = s; return r; }

// ---------------------------------------------------------------------------
// Packed FP32 (VOP3P) primitives — R4-harness-proven byte semantics.
// Coefficient quadruple (c,sn,sp,cp) sits in an aligned VGPR pair
// (c,sn)|(sp,cp); op_sel/op_sel_hi give free per-half splats, neg_lo free
// negation, swapped reads in pk_fma_rot give the i*t swizzle. 6 VOP3P ops
// per pair rotation; v_pk_fma_f32 is double-rate FP32 on CDNA.
// ---------------------------------------------------------------------------
// d = ab.lo * x
__device__ __forceinline__ v2f pk_mul_lo(v2f ab, v2f x) {
    v2f d;
    asm("v_pk_mul_f32 %0, %1, %2 op_sel:[0,0] op_sel_hi:[0,1]"
        : "=v"(d) : "v"(ab), "v"(x));
    return d;
}
// d = -ab.hi * x + acc
__device__ __forceinline__ v2f pk_fnma_hi(v2f ab, v2f x, v2f acc) {
    v2f d;
    asm("v_pk_fma_f32 %0, %1, %2, %3 op_sel:[1,0,0] op_sel_hi:[1,1,1] neg_lo:[1,0,0] neg_hi:[1,0,0]"
        : "=v"(d) : "v"(ab), "v"(x), "v"(acc));
    return d;
}
// d = ab.hi * x + acc
__device__ __forceinline__ v2f pk_fma_hi(v2f ab, v2f x, v2f acc) {
    v2f d;
    asm("v_pk_fma_f32 %0, %1, %2, %3 op_sel:[1,0,0] op_sel_hi:[1,1,1]"
        : "=v"(d) : "v"(ab), "v"(x), "v"(acc));
    return d;
}
// d.lo = -pc.hi*t.hi + m.lo ; d.hi = pc.hi*t.lo + m.hi   (A' = (sp+i*cp)*t, cp part)
__device__ __forceinline__ v2f pk_fma_rot(v2f pc, v2f t, v2f m) {
    v2f d;
    asm("v_pk_fma_f32 %0, %1, %2, %3 op_sel:[1,1,0] op_sel_hi:[1,0,1] neg_lo:[1,0,0]"
        : "=v"(d) : "v"(pc), "v"(t), "v"(m));
    return d;
}

union f4p { float4 f; v2f h[2]; };   // h[0]=(c,sn), h[1]=(sp,cp)

// Full pair rotation: t = c*A - sn*B;  B' = c*B + sn*A;  A' = (sp+i*cp)*t
__device__ __forceinline__ void pair_rotp(const float4 f, v2f& A, v2f& B) {
    f4p u; u.f = f;
    v2f t  = pk_mul_lo(u.h[0], A);
    t      = pk_fnma_hi(u.h[0], B, t);
    v2f b2 = pk_mul_lo(u.h[0], B);
    B      = pk_fma_hi(u.h[0], A, b2);    // uses original A
    v2f m  = pk_mul_lo(u.h[1], t);
    A      = pk_fma_rot(u.h[1], t, m);
}
// Right-boundary variant: update A only, Bn is neighbor's value.
__device__ __forceinline__ void pair_rotp_a(const float4 f, v2f& A, const v2f Bn) {
    f4p u; u.f = f;
    v2f t = pk_mul_lo(u.h[0], A);
    t     = pk_fnma_hi(u.h[0], Bn, t);
    v2f m = pk_mul_lo(u.h[1], t);
    A     = pk_fma_rot(u.h[1], t, m);
}

// Wave-level DPP lane shifts (single VALU op; proven exact + neutral-cost).
__device__ __forceinline__ float dpp_up1(float v) {   // lane n <- lane n-1
    int i = __builtin_bit_cast(int, v);
    int r = __builtin_amdgcn_update_dpp(i, i, 0x138, 0xF, 0xF, false);  // wave_shr:1
    return __builtin_bit_cast(float, r);
}
__device__ __forceinline__ float dpp_dn1(float v) {   // lane n <- lane n+1
    int i = __builtin_bit_cast(int, v);
    int r = __builtin_amdgcn_update_dpp(i, i, 0x130, 0xF, 0xF, false);  // wave_shl:1
    return __builtin_bit_cast(float, r);
}

// ---------------------------------------------------------------------------
// Kernel 1: merged coefficient table (R5 layout, proven):
//   ctab[s*1024 + slot]        even pair p, slot = ((p&7)<<6)|(p>>3)
//   ctab[s*1024 + 512 + slot]  odd  pair j, same slot formula; j==511 -> identity
//   wtab[q][lane] float4 = (cw0,sw0,cw1,sw1) for cols (16*lane+2q, +2q+1)
// ---------------------------------------------------------------------------
__global__ void coeff_kernel(const float* __restrict__ omega,
                             const float* __restrict__ ETh,
                             const float* __restrict__ OTh,
                             const float* __restrict__ EPh,
                             const float* __restrict__ OPh,
                             float4* __restrict__ ctab,
                             float2* __restrict__ wtab)
{
    int idx = blockIdx.x * 256 + threadIdx.x;
    if (idx < NSTEP * 512) {
        int s = idx >> 9;
        int p = idx & 511;
        float c, sn, cp, sp;
        __sincosf(ETh[idx], &sn, &c);
        __sincosf(EPh[idx], &sp, &cp);
        ctab[(s << 10) | ((p & 7) << 6) | (p >> 3)] = make_float4(c, sn, sp, cp);
    } else if (idx < 2 * NSTEP * 512) {
        int i2 = idx - NSTEP * 512;
        int s = i2 >> 9;
        int j = i2 & 511;
        float4 v;
        if (j < OHH) {
            float c, sn, cp, sp;
            __sincosf(OTh[s * OHH + j], &sn, &c);
            __sincosf(OPh[s * OHH + j], &sp, &cp);
            v = make_float4(c, sn, sp, cp);
        } else {
            v = make_float4(1.f, 0.f, 1.f, 0.f);  // identity rotation
        }
        ctab[(s << 10) | 512 | ((j & 7) << 6) | (j >> 3)] = v;
    } else if (idx < 2 * NSTEP * 512 + HDIM) {
        int c = idx - 2 * NSTEP * 512;
        float cw, sw;
        __sincosf(omega[c], &sw, &cw);
        int p = c >> 1;
        wtab[(((p & 7) << 6) | (p >> 3)) * 2 + (c & 1)] = make_float2(cw, sw);
    }
}

// ---------------------------------------------------------------------------
// Kernel 2: champion geometry (2 rows/wave, 4 waves/block, 256 blocks, no
// LDS, no barriers) + pk-math + oc0-via-DPP (16 loads/step) + merged ctab.
//
// Final model (fits R0-R7): per-CU L1 fill path is MLP-capped at ~32-42
// B/cyc; wall = 64-68 KB coeff/CU/step / ~32 B/cyc ~= 2050-2180 cyc; VALU
// (~1000) hides beneath. R3: more outstanding/wave = neutral (cap is per-CU).
// R7: 2x waves = 2x traffic at only ~1.35x rate -> worse. R5: L2-direct
// slower. R2/R6: LDS route trades the cap for barrier/serialization of the
// same magnitude. This round: -6% bytes (drop 17th load), -50% VALU
// (insurance against partial VALU exposure), restore champion geometry.
// ---------------------------------------------------------------------------
__global__ __launch_bounds__(256, 1) void eunn_kernel(
    const float* __restrict__ x_re,
    const float* __restrict__ x_im,
    const float4* __restrict__ ctab,
    const float4* __restrict__ wtab,
    float* __restrict__ out)
{
    const int lane = threadIdx.x & 63;
    const int wave = threadIdx.x >> 6;
    const int row0 = blockIdx.x * 8 + wave * 2;
    const int colbase = lane << 4;

    v2f x[2][16];   // interleaved (re, im) state

    // current / next step coefficient register sets (16 float4 each)
    float4 cec[8], coc[8];
    float4 nec[8], noc[8];

    // --- prologue: issue step-0 coefficient loads first
    {
        const float4* b = ctab + lane;
        #pragma unroll
        for (int k = 0; k < 8; ++k) cec[k] = b[k << 6];
        #pragma unroll
        for (int k = 0; k < 8; ++k) coc[k] = b[512 + (k << 6)];
    }

    // --- load state (f32 planes), interleave into v2f regs ---
    #pragma unroll
    for (int r = 0; r < 2; ++r) {
        const float4* pr = reinterpret_cast<const float4*>(x_re + (row0 + r) * HDIM + colbase);
        const float4* pi = reinterpret_cast<const float4*>(x_im + (row0 + r) * HDIM + colbase);
        #pragma unroll
        for (int q = 0; q < 4; ++q) {
            float4 vr = pr[q];
            float4 vi = pi[q];
            x[r][4*q+0].x = vr.x; x[r][4*q+0].y = vi.x;
            x[r][4*q+1].x = vr.y; x[r][4*q+1].y = vi.y;
            x[r][4*q+2].x = vr.z; x[r][4*q+2].y = vi.z;
            x[r][4*q+3].x = vr.w; x[r][4*q+3].y = vi.w;
        }
    }

    // one full step's math with coefficient set (ec, oc)
    auto body = [&](const float4 (&ec)[8], const float4 (&oc)[8]) {
        // ---- even layer, boundary pairs first (k=0,7)
        pair_rotp(ec[0], x[0][0],  x[0][1]);
        pair_rotp(ec[0], x[1][0],  x[1][1]);
        pair_rotp(ec[7], x[0][14], x[0][15]);
        pair_rotp(ec[7], x[1][14], x[1][15]);

        // boundary exchange on post-even values via DPP
        v2f xn[2], xl[2];
        #pragma unroll
        for (int r = 0; r < 2; ++r) {
            xn[r].x = dpp_dn1(x[r][0].x);    // right neighbor's col0
            xn[r].y = dpp_dn1(x[r][0].y);
            xl[r].x = dpp_up1(x[r][15].x);   // left neighbor's col15
            xl[r].y = dpp_up1(x[r][15].y);
        }

        // oc0 (left-boundary coeffs = lane-1's oc[7]) via DPP; lane0 -> identity
        float c0 = dpp_up1(oc[7].x);
        float s0 = dpp_up1(oc[7].y);
        if (lane == 0) { c0 = 1.0f; s0 = 0.0f; }

        // remaining even pairs k=1..6
        #pragma unroll
        for (int k = 1; k < 7; ++k) {
            pair_rotp(ec[k], x[0][2*k], x[0][2*k+1]);
            pair_rotp(ec[k], x[1][2*k], x[1][2*k+1]);
        }

        // ---- odd layer: internal pairs oc[k-1] -> local cols (2k-1, 2k)
        #pragma unroll
        for (int k = 1; k < 8; ++k) {
            pair_rotp(oc[k-1], x[0][2*k-1], x[0][2*k]);
            pair_rotp(oc[k-1], x[1][2*k-1], x[1][2*k]);
        }
        // right boundary: update col15 (lane63: oc[7] identity pad, sn=0)
        pair_rotp_a(oc[7], x[0][15], xn[0]);
        pair_rotp_a(oc[7], x[1][15], xn[1]);
        // left boundary: update col0 (lane0: forced identity above)
        {
            v2f C = vsplat(c0), S = vsplat(s0);
            x[0][0] = C * x[0][0] + S * xl[0];
            x[1][0] = C * x[1][0] + S * xl[1];
        }
    };

    // 2-step unrolled main loop; coefficient loads issued one full step
    // before first use, pinned by sched_barrier so they cannot sink.
    for (int s = 0; s < NSTEP; s += 2) {
        {   // prefetch step s+1 -> n-set
            const float4* b = ctab + ((s + 1) << 10) + lane;
            #pragma unroll
            for (int k = 0; k < 8; ++k) nec[k] = b[k << 6];
            #pragma unroll
            for (int k = 0; k < 8; ++k) noc[k] = b[512 + (k << 6)];
        }
        __builtin_amdgcn_sched_barrier(0);
        body(cec, coc);

        {   // prefetch step s+2 -> c-set (clamped; last-iter loads unused but valid)
            int s2 = (s + 2 < NSTEP) ? (s + 2) : (NSTEP - 1);
            const float4* b = ctab + (s2 << 10) + lane;
            #pragma unroll
            for (int k = 0; k < 8; ++k) cec[k] = b[k << 6];
            #pragma unroll
            for (int k = 0; k < 8; ++k) coc[k] = b[512 + (k << 6)];
        }
        __builtin_amdgcn_sched_barrier(0);
        body(nec, noc);
    }

    // --- omega phase + de-interleave + store (coalesced) ---
    float4 wc[8];
    #pragma unroll
    for (int q = 0; q < 8; ++q) wc[q] = wtab[(q << 6) + lane];  // (cw0,sw0,cw1,sw1) cols 2q,2q+1

    #pragma unroll
    for (int r = 0; r < 2; ++r) {
        float4* pre = reinterpret_cast<float4*>(out + (row0 + r) * HDIM + colbase);
        float4* pim = reinterpret_cast<float4*>(out + BDIM * HDIM + (row0 + r) * HDIM + colbase);
        #pragma unroll
        for (int h = 0; h < 4; ++h) {
            float4 wa = wc[2*h];      // cols 4h, 4h+1
            float4 wb = wc[2*h + 1];  // cols 4h+2, 4h+3
            v2f X0 = x[r][4*h+0], X1 = x[r][4*h+1], X2 = x[r][4*h+2], X3 = x[r][4*h+3];
            float4 vr, vi;
            vr.x = X0.x * wa.x - X0.y * wa.y;  vi.x = X0.x * wa.y + X0.y * wa.x;
            vr.y = X1.x * wa.z - X1.y * wa.w;  vi.y = X1.x * wa.w + X1.y * wa.z;
            vr.z = X2.x * wb.x - X2.y * wb.y;  vi.z = X2.x * wb.y + X2.y * wb.x;
            vr.w = X3.x * wb.z - X3.y * wb.w;  vi.w = X3.x * wb.w + X3.y * wb.z;
            pre[h] = vr;
            pim[h] = vi;
        }
    }
}

extern "C" void kernel_launch(void* const* d_in, const int* in_sizes, int n_in,
                              void* d_out, int out_size, void* d_ws, size_t ws_size,
                              hipStream_t stream)
{
    const float* x_re  = (const float*)d_in[0];
    const float* x_im  = (const float*)d_in[1];
    const float* omega = (const float*)d_in[2];
    const float* eth   = (const float*)d_in[3];
    const float* oth   = (const float*)d_in[4];
    const float* eph   = (const float*)d_in[5];
    const float* oph   = (const float*)d_in[6];

    char* ws = (char*)d_ws;
    float4* ctab = (float4*)ws;                             // 64*1024*16 = 1 MB
    float2* wtab = (float2*)(ws + NSTEP * 1024 * 16);       // 8 KB

    coeff_kernel<<<260, 256, 0, stream>>>(omega, eth, oth, eph, oph, ctab, wtab);
    eunn_kernel<<<BDIM / 8, 256, 0, stream>>>(x_re, x_im, ctab,
                                              (const float4*)wtab, (float*)d_out);
}